// Round 1
// baseline (1585.090 us; speedup 1.0000x reference)
//
#include <hip/hip_runtime.h>

#define T_TOK 4096
#define DM 2048
#define DF 8192
#define NE 4
#define BM 128
#define BN 64
#define BK 32
#define MAX_TILES 36
#define LDK (BK + 8)   // 40 shorts: 80B row stride, 16B-aligned, ~2-way banks

typedef __attribute__((ext_vector_type(8))) short short8;
typedef __attribute__((ext_vector_type(4))) float f32x4;

__device__ __forceinline__ unsigned short f2bf(float f) {
  unsigned int u = __float_as_uint(f);
  u += 0x7fffu + ((u >> 16) & 1u);   // round-to-nearest-even
  return (unsigned short)(u >> 16);
}

// ---------------- router: one wave per token, fp32 ----------------
__global__ __launch_bounds__(256) void router_kernel(
    const float* __restrict__ x, const float* __restrict__ Wr,
    const float* __restrict__ br, int* __restrict__ top_idx,
    float* __restrict__ top_w, int* __restrict__ counts) {
  int tok = (blockIdx.x * blockDim.x + threadIdx.x) >> 6;
  int lane = threadIdx.x & 63;
  if (tok >= T_TOK) return;
  const float* xr = x + (size_t)tok * DM;
  float s0 = 0.f, s1 = 0.f, s2 = 0.f, s3 = 0.f;
  for (int j = lane; j < DM; j += 64) {
    float xv = xr[j];
    float4 w = *(const float4*)(Wr + (size_t)j * NE);
    s0 += xv * w.x; s1 += xv * w.y; s2 += xv * w.z; s3 += xv * w.w;
  }
#pragma unroll
  for (int off = 32; off > 0; off >>= 1) {
    s0 += __shfl_xor(s0, off);
    s1 += __shfl_xor(s1, off);
    s2 += __shfl_xor(s2, off);
    s3 += __shfl_xor(s3, off);
  }
  if (lane == 0) {
    float l[NE] = {s0 + br[0], s1 + br[1], s2 + br[2], s3 + br[3]};
    int bi = 0; float bm = l[0];
#pragma unroll
    for (int e = 1; e < NE; e++) if (l[e] > bm) { bm = l[e]; bi = e; }
    float s = 0.f;
#pragma unroll
    for (int e = 0; e < NE; e++) s += __expf(l[e] - bm);
    top_idx[tok] = bi;
    top_w[tok] = 1.0f / s;   // softmax prob of argmax
    atomicAdd(&counts[bi], 1);
  }
}

// ---------------- scan: offsets + tile descriptors (1 thread) ----------------
__global__ void scan_kernel(const int* __restrict__ counts, int* __restrict__ offs,
                            int* __restrict__ cursors, int* __restrict__ tiles) {
  if (threadIdx.x != 0 || blockIdx.x != 0) return;
  int offv[NE + 1];
  offv[0] = 0;
  for (int e = 0; e < NE; e++) offv[e + 1] = offv[e] + counts[e];
  for (int e = 0; e <= NE; e++) offs[e] = offv[e];
  for (int e = 0; e < NE; e++) cursors[e] = offv[e];
  int nt = 0;
  for (int e = 0; e < NE; e++) {
    int c = counts[e];
    for (int s = 0; s < c; s += BM) {
      tiles[nt * 3 + 0] = e;
      tiles[nt * 3 + 1] = offv[e] + s;
      tiles[nt * 3 + 2] = (c - s < BM) ? (c - s) : BM;
      nt++;
    }
  }
  for (; nt < MAX_TILES; nt++) {
    tiles[nt * 3 + 0] = 0; tiles[nt * 3 + 1] = 0; tiles[nt * 3 + 2] = 0;
  }
}

// ---------------- scatter: token -> sorted slot ----------------
__global__ __launch_bounds__(256) void scatter_kernel(
    const int* __restrict__ top_idx, int* __restrict__ cursors,
    int* __restrict__ sorted) {
  int t = blockIdx.x * blockDim.x + threadIdx.x;
  if (t >= T_TOK) return;
  int e = top_idx[t];
  int p = atomicAdd(&cursors[e], 1);
  sorted[p] = t;
}

// ---------------- gemm1: h = silu(x@Wg) * (x@Wu), bf16 out ----------------
__global__ __launch_bounds__(256) void gemm1_kernel(
    const float* __restrict__ x, const float* __restrict__ Wg,
    const float* __restrict__ Wu, const int* __restrict__ tiles,
    const int* __restrict__ sorted, unsigned short* __restrict__ hbuf) {
  const int slot = blockIdx.x;
  const int e = tiles[slot * 3 + 0];
  const int row0 = tiles[slot * 3 + 1];
  const int nvalid = tiles[slot * 3 + 2];
  if (nvalid == 0) return;
  const int n0 = blockIdx.y * BN;

  __shared__ __align__(16) unsigned short As[BM][LDK];
  __shared__ __align__(16) unsigned short Bg[BN][LDK];
  __shared__ __align__(16) unsigned short Bu[BN][LDK];

  const int t = threadIdx.x;
  // A loader: 8 threads per row, float4 each; 4 row-groups of 32
  const int arow = t >> 3;
  const int ac = (t & 7) << 2;
  int atok[4];
#pragma unroll
  for (int r = 0; r < 4; r++) {
    int row = arow + (r << 5);
    atok[r] = (row < nvalid) ? sorted[row0 + row] : -1;
  }
  // B loader: thread owns column n=t&63, k-octet base (t>>6)*8
  const int bn = t & 63;
  const int bk8 = (t >> 6) << 3;

  const size_t eo = (size_t)e * DM * DF;
  const float* __restrict__ Wge = Wg + eo;
  const float* __restrict__ Wue = Wu + eo;

  const int wv = t >> 6, lane = t & 63;
  const int wrow = (wv >> 1) << 6, wcol = (wv & 1) << 5;
  const int lr = lane & 15, lk = (lane >> 4) << 3;

  f32x4 accg[4][2], accu[4][2];
#pragma unroll
  for (int mi = 0; mi < 4; mi++)
#pragma unroll
    for (int ni = 0; ni < 2; ni++) {
      accg[mi][ni] = (f32x4){0.f, 0.f, 0.f, 0.f};
      accu[mi][ni] = (f32x4){0.f, 0.f, 0.f, 0.f};
    }

  for (int k0 = 0; k0 < DM; k0 += BK) {
    // stage A (gathered x rows), fp32 -> bf16
#pragma unroll
    for (int r = 0; r < 4; r++) {
      float4 v = make_float4(0.f, 0.f, 0.f, 0.f);
      if (atok[r] >= 0) v = *(const float4*)(x + (size_t)atok[r] * DM + k0 + ac);
      ushort4 pv;
      pv.x = f2bf(v.x); pv.y = f2bf(v.y); pv.z = f2bf(v.z); pv.w = f2bf(v.w);
      *(ushort4*)&As[arow + (r << 5)][ac] = pv;
    }
    // stage B (Wg, Wu): 4 k-contiguous values per write -> b64 LDS writes
#pragma unroll
    for (int half = 0; half < 2; half++) {
      int kb = bk8 + half * 4;
      const float* pg = Wge + (size_t)(k0 + kb) * DF + n0 + bn;
      const float* pu = Wue + (size_t)(k0 + kb) * DF + n0 + bn;
      ushort4 vg, vu;
      vg.x = f2bf(pg[0]);              vu.x = f2bf(pu[0]);
      vg.y = f2bf(pg[(size_t)DF]);     vu.y = f2bf(pu[(size_t)DF]);
      vg.z = f2bf(pg[(size_t)2 * DF]); vu.z = f2bf(pu[(size_t)2 * DF]);
      vg.w = f2bf(pg[(size_t)3 * DF]); vu.w = f2bf(pu[(size_t)3 * DF]);
      *(ushort4*)&Bg[bn][kb] = vg;
      *(ushort4*)&Bu[bn][kb] = vu;
    }
    __syncthreads();

    short8 af[4], bgf[2], buf2[2];
#pragma unroll
    for (int mi = 0; mi < 4; mi++)
      af[mi] = *(const short8*)&As[wrow + (mi << 4) + lr][lk];
#pragma unroll
    for (int ni = 0; ni < 2; ni++) {
      bgf[ni]  = *(const short8*)&Bg[wcol + (ni << 4) + lr][lk];
      buf2[ni] = *(const short8*)&Bu[wcol + (ni << 4) + lr][lk];
    }
#pragma unroll
    for (int mi = 0; mi < 4; mi++)
#pragma unroll
      for (int ni = 0; ni < 2; ni++) {
        accg[mi][ni] = __builtin_amdgcn_mfma_f32_16x16x32_bf16(af[mi], bgf[ni], accg[mi][ni], 0, 0, 0);
        accu[mi][ni] = __builtin_amdgcn_mfma_f32_16x16x32_bf16(af[mi], buf2[ni], accu[mi][ni], 0, 0, 0);
      }
    __syncthreads();
  }

  // epilogue: h = silu(g)*u -> bf16
  const int l4 = (lane >> 4) << 2;
#pragma unroll
  for (int mi = 0; mi < 4; mi++) {
#pragma unroll
    for (int r = 0; r < 4; r++) {
      int lrow = wrow + (mi << 4) + l4 + r;
      if (lrow < nvalid) {
        size_t base = (size_t)(row0 + lrow) * DF + n0 + wcol + lr;
#pragma unroll
        for (int ni = 0; ni < 2; ni++) {
          float g = accg[mi][ni][r];
          float u = accu[mi][ni][r];
          float hv = (g / (1.f + __expf(-g))) * u;
          hbuf[base + (ni << 4)] = f2bf(hv);
        }
      }
    }
  }
}

// ---------------- gemm2: out[token] = (h @ Wd) * top_w ----------------
__global__ __launch_bounds__(256) void gemm2_kernel(
    const unsigned short* __restrict__ hbuf, const float* __restrict__ Wd,
    const int* __restrict__ tiles, const int* __restrict__ sorted,
    const float* __restrict__ topw, float* __restrict__ out) {
  const int slot = blockIdx.x;
  const int e = tiles[slot * 3 + 0];
  const int row0 = tiles[slot * 3 + 1];
  const int nvalid = tiles[slot * 3 + 2];
  if (nvalid == 0) return;
  const int n0 = blockIdx.y * BN;

  __shared__ __align__(16) unsigned short As[BM][LDK];
  __shared__ __align__(16) unsigned short Bs[BN][LDK];

  const int t = threadIdx.x;
  const int arow = t >> 3;
  const int ac = (t & 7) << 2;
  const int bn = t & 63;
  const int bk8 = (t >> 6) << 3;
  const float* __restrict__ Wde = Wd + (size_t)e * DF * DM;

  const int wv = t >> 6, lane = t & 63;
  const int wrow = (wv >> 1) << 6, wcol = (wv & 1) << 5;
  const int lr = lane & 15, lk = (lane >> 4) << 3;

  f32x4 acc[4][2];
#pragma unroll
  for (int mi = 0; mi < 4; mi++)
#pragma unroll
    for (int ni = 0; ni < 2; ni++) acc[mi][ni] = (f32x4){0.f, 0.f, 0.f, 0.f};

  for (int k0 = 0; k0 < DF; k0 += BK) {
    // stage A from h (already bf16, rows contiguous in sorted space)
#pragma unroll
    for (int r = 0; r < 4; r++) {
      int row = arow + (r << 5);
      ushort4 pv; pv.x = 0; pv.y = 0; pv.z = 0; pv.w = 0;
      if (row < nvalid)
        pv = *(const ushort4*)(hbuf + (size_t)(row0 + row) * DF + k0 + ac);
      *(ushort4*)&As[row][ac] = pv;
    }
    // stage B from Wd
#pragma unroll
    for (int half = 0; half < 2; half++) {
      int kb = bk8 + half * 4;
      const float* pd = Wde + (size_t)(k0 + kb) * DM + n0 + bn;
      ushort4 vd;
      vd.x = f2bf(pd[0]);
      vd.y = f2bf(pd[(size_t)DM]);
      vd.z = f2bf(pd[(size_t)2 * DM]);
      vd.w = f2bf(pd[(size_t)3 * DM]);
      *(ushort4*)&Bs[bn][kb] = vd;
    }
    __syncthreads();

    short8 af[4], bf2[2];
#pragma unroll
    for (int mi = 0; mi < 4; mi++)
      af[mi] = *(const short8*)&As[wrow + (mi << 4) + lr][lk];
#pragma unroll
    for (int ni = 0; ni < 2; ni++)
      bf2[ni] = *(const short8*)&Bs[wcol + (ni << 4) + lr][lk];
#pragma unroll
    for (int mi = 0; mi < 4; mi++)
#pragma unroll
      for (int ni = 0; ni < 2; ni++)
        acc[mi][ni] = __builtin_amdgcn_mfma_f32_16x16x32_bf16(af[mi], bf2[ni], acc[mi][ni], 0, 0, 0);
    __syncthreads();
  }

  const int l4 = (lane >> 4) << 2;
#pragma unroll
  for (int mi = 0; mi < 4; mi++) {
#pragma unroll
    for (int r = 0; r < 4; r++) {
      int lrow = wrow + (mi << 4) + l4 + r;
      if (lrow < nvalid) {
        int tok = sorted[row0 + lrow];
        float w = topw[tok];
        size_t base = (size_t)tok * DM + n0 + wcol + lr;
#pragma unroll
        for (int ni = 0; ni < 2; ni++)
          out[base + (ni << 4)] = acc[mi][ni][r] * w;
      }
    }
  }
}

extern "C" void kernel_launch(void* const* d_in, const int* in_sizes, int n_in,
                              void* d_out, int out_size, void* d_ws, size_t ws_size,
                              hipStream_t stream) {
  const float* x  = (const float*)d_in[0];
  const float* Wr = (const float*)d_in[1];
  const float* br = (const float*)d_in[2];
  const float* Wg = (const float*)d_in[3];
  const float* Wu = (const float*)d_in[4];
  const float* Wd = (const float*)d_in[5];
  float* out = (float*)d_out;

  // workspace layout
  const size_t H_BYTES = (size_t)T_TOK * DF * 2;        // 64 MiB bf16 h
  unsigned short* hbuf = (unsigned short*)d_ws;
  int* meta = (int*)((char*)d_ws + H_BYTES);
  int* top_idx = meta;                 // 4096
  int* sorted  = meta + 4096;          // 4096
  int* counts  = meta + 8192;          // 4
  int* offs    = meta + 8196;          // 5
  int* cursors = meta + 8201;          // 4  (realigned below? int-granular is fine)
  int* tiles   = meta + 8208;          // 36*3 = 108
  float* topw  = (float*)(meta + 8320);// 4096

  hipMemsetAsync(counts, 0, NE * sizeof(int), stream);
  router_kernel<<<dim3((T_TOK * 64) / 256), 256, 0, stream>>>(x, Wr, br, top_idx, topw, counts);
  scan_kernel<<<1, 1, 0, stream>>>(counts, offs, cursors, tiles);
  scatter_kernel<<<dim3(T_TOK / 256), 256, 0, stream>>>(top_idx, cursors, sorted);
  gemm1_kernel<<<dim3(MAX_TILES, DF / BN), 256, 0, stream>>>(x, Wg, Wu, tiles, sorted, hbuf);
  gemm2_kernel<<<dim3(MAX_TILES, DM / BN), 256, 0, stream>>>(hbuf, Wd, tiles, sorted, topw, out);
}

// Round 2
// 1287.717 us; speedup vs baseline: 1.2309x; 1.2309x over previous
//
#include <hip/hip_runtime.h>

#define T_TOK 4096
#define DM 2048
#define DF 8192
#define NE 4
#define BM 256
#define BN 64
#define BK 32
#define MAX_TILES 20
#define LDK (BK + 8)   // 40 shorts: 80B row stride, 16B-aligned

typedef __attribute__((ext_vector_type(8))) short short8;
typedef __attribute__((ext_vector_type(4))) float f32x4;

__device__ __forceinline__ unsigned short f2bf(float f) {
  unsigned int u = __float_as_uint(f);
  u += 0x7fffu + ((u >> 16) & 1u);   // round-to-nearest-even
  return (unsigned short)(u >> 16);
}

// ---------------- router: one wave per token, fp32 ----------------
__global__ __launch_bounds__(256) void router_kernel(
    const float* __restrict__ x, const float* __restrict__ Wr,
    const float* __restrict__ br, int* __restrict__ top_idx,
    float* __restrict__ top_w, int* __restrict__ counts) {
  int tok = (blockIdx.x * blockDim.x + threadIdx.x) >> 6;
  int lane = threadIdx.x & 63;
  if (tok >= T_TOK) return;
  const float* xr = x + (size_t)tok * DM;
  float s0 = 0.f, s1 = 0.f, s2 = 0.f, s3 = 0.f;
  for (int j = lane; j < DM; j += 64) {
    float xv = xr[j];
    float4 w = *(const float4*)(Wr + (size_t)j * NE);
    s0 += xv * w.x; s1 += xv * w.y; s2 += xv * w.z; s3 += xv * w.w;
  }
#pragma unroll
  for (int off = 32; off > 0; off >>= 1) {
    s0 += __shfl_xor(s0, off);
    s1 += __shfl_xor(s1, off);
    s2 += __shfl_xor(s2, off);
    s3 += __shfl_xor(s3, off);
  }
  if (lane == 0) {
    float l[NE] = {s0 + br[0], s1 + br[1], s2 + br[2], s3 + br[3]};
    int bi = 0; float bm = l[0];
#pragma unroll
    for (int e = 1; e < NE; e++) if (l[e] > bm) { bm = l[e]; bi = e; }
    float s = 0.f;
#pragma unroll
    for (int e = 0; e < NE; e++) s += __expf(l[e] - bm);
    top_idx[tok] = bi;
    top_w[tok] = 1.0f / s;   // softmax prob of argmax
    atomicAdd(&counts[bi], 1);
  }
}

// ---------------- scan: offsets + tile descriptors (1 thread) ----------------
__global__ void scan_kernel(const int* __restrict__ counts, int* __restrict__ offs,
                            int* __restrict__ cursors, int* __restrict__ tiles) {
  if (threadIdx.x != 0 || blockIdx.x != 0) return;
  int offv[NE + 1];
  offv[0] = 0;
  for (int e = 0; e < NE; e++) offv[e + 1] = offv[e] + counts[e];
  for (int e = 0; e <= NE; e++) offs[e] = offv[e];
  for (int e = 0; e < NE; e++) cursors[e] = offv[e];
  int nt = 0;
  for (int e = 0; e < NE; e++) {
    int c = counts[e];
    for (int s = 0; s < c; s += BM) {
      tiles[nt * 3 + 0] = e;
      tiles[nt * 3 + 1] = offv[e] + s;
      tiles[nt * 3 + 2] = (c - s < BM) ? (c - s) : BM;
      nt++;
    }
  }
  for (; nt < MAX_TILES; nt++) {
    tiles[nt * 3 + 0] = 0; tiles[nt * 3 + 1] = 0; tiles[nt * 3 + 2] = 0;
  }
}

// ---------------- scatter: token -> sorted slot ----------------
__global__ __launch_bounds__(256) void scatter_kernel(
    const int* __restrict__ top_idx, int* __restrict__ cursors,
    int* __restrict__ sorted) {
  int t = blockIdx.x * blockDim.x + threadIdx.x;
  if (t >= T_TOK) return;
  int e = top_idx[t];
  int p = atomicAdd(&cursors[e], 1);
  sorted[p] = t;
}

// ---------------- gemm1: h = silu(x@Wg) * (x@Wu), bf16 out ----------------
// 512 threads, 8 waves as 4M x 2N; wave tile 64x32; BM=256 halves weight re-reads.
__global__ __launch_bounds__(512, 4) void gemm1_kernel(
    const float* __restrict__ x, const float* __restrict__ Wg,
    const float* __restrict__ Wu, const int* __restrict__ tiles,
    const int* __restrict__ sorted, unsigned short* __restrict__ hbuf) {
  const int slot = blockIdx.x;
  const int e = tiles[slot * 3 + 0];
  const int row0 = tiles[slot * 3 + 1];
  const int nvalid = tiles[slot * 3 + 2];
  if (nvalid == 0) return;
  const int n0 = blockIdx.y * BN;

  __shared__ __align__(16) unsigned short As[BM][LDK];
  __shared__ __align__(16) unsigned short Bg[BN][LDK];
  __shared__ __align__(16) unsigned short Bu[BN][LDK];

  const int t = threadIdx.x;
  // A loader: 2 threads per row, each covers 16 k-cols (4x float4)
  const int arow = t >> 1;
  const int ah = (t & 1) << 4;
  const int atok = (arow < nvalid) ? sorted[row0 + arow] : -1;
  const float* __restrict__ xrow = x + (size_t)(atok >= 0 ? atok : 0) * DM;
  // B loader: thread owns column n=t&63, k-quad base (t>>6)*4
  const int bn = t & 63;
  const int bkq = (t >> 6) << 2;

  const size_t eo = (size_t)e * DM * DF;
  const float* __restrict__ Wge = Wg + eo;
  const float* __restrict__ Wue = Wu + eo;

  const int wv = t >> 6, lane = t & 63;
  const int wrow = (wv >> 1) << 6, wcol = (wv & 1) << 5;
  const int lr = lane & 15, lk = (lane >> 4) << 3;

  f32x4 accg[4][2], accu[4][2];
#pragma unroll
  for (int mi = 0; mi < 4; mi++)
#pragma unroll
    for (int ni = 0; ni < 2; ni++) {
      accg[mi][ni] = (f32x4){0.f, 0.f, 0.f, 0.f};
      accu[mi][ni] = (f32x4){0.f, 0.f, 0.f, 0.f};
    }

  for (int k0 = 0; k0 < DM; k0 += BK) {
    // stage A (gathered x rows), fp32 -> bf16: 4x float4 -> 4x ushort4
#pragma unroll
    for (int j = 0; j < 4; j++) {
      float4 v = make_float4(0.f, 0.f, 0.f, 0.f);
      if (atok >= 0) v = *(const float4*)(xrow + k0 + ah + (j << 2));
      ushort4 pv;
      pv.x = f2bf(v.x); pv.y = f2bf(v.y); pv.z = f2bf(v.z); pv.w = f2bf(v.w);
      *(ushort4*)&As[arow][ah + (j << 2)] = pv;
    }
    // stage B (Wg, Wu): 4 k-contiguous values per matrix -> b64 LDS writes
    {
      const float* pg = Wge + (size_t)(k0 + bkq) * DF + n0 + bn;
      const float* pu = Wue + (size_t)(k0 + bkq) * DF + n0 + bn;
      ushort4 vg, vu;
      vg.x = f2bf(pg[0]);              vu.x = f2bf(pu[0]);
      vg.y = f2bf(pg[(size_t)DF]);     vu.y = f2bf(pu[(size_t)DF]);
      vg.z = f2bf(pg[(size_t)2 * DF]); vu.z = f2bf(pu[(size_t)2 * DF]);
      vg.w = f2bf(pg[(size_t)3 * DF]); vu.w = f2bf(pu[(size_t)3 * DF]);
      *(ushort4*)&Bg[bn][bkq] = vg;
      *(ushort4*)&Bu[bn][bkq] = vu;
    }
    __syncthreads();

    short8 af[4], bgf[2], buf2[2];
#pragma unroll
    for (int mi = 0; mi < 4; mi++)
      af[mi] = *(const short8*)&As[wrow + (mi << 4) + lr][lk];
#pragma unroll
    for (int ni = 0; ni < 2; ni++) {
      bgf[ni]  = *(const short8*)&Bg[wcol + (ni << 4) + lr][lk];
      buf2[ni] = *(const short8*)&Bu[wcol + (ni << 4) + lr][lk];
    }
#pragma unroll
    for (int mi = 0; mi < 4; mi++)
#pragma unroll
      for (int ni = 0; ni < 2; ni++) {
        accg[mi][ni] = __builtin_amdgcn_mfma_f32_16x16x32_bf16(af[mi], bgf[ni], accg[mi][ni], 0, 0, 0);
        accu[mi][ni] = __builtin_amdgcn_mfma_f32_16x16x32_bf16(af[mi], buf2[ni], accu[mi][ni], 0, 0, 0);
      }
    __syncthreads();
  }

  // epilogue: h = silu(g)*u -> bf16
  const int l4 = (lane >> 4) << 2;
#pragma unroll
  for (int mi = 0; mi < 4; mi++) {
#pragma unroll
    for (int r = 0; r < 4; r++) {
      int lrow = wrow + (mi << 4) + l4 + r;
      if (lrow < nvalid) {
        size_t base = (size_t)(row0 + lrow) * DF + n0 + wcol + lr;
#pragma unroll
        for (int ni = 0; ni < 2; ni++) {
          float g = accg[mi][ni][r];
          float u = accu[mi][ni][r];
          float hv = (g / (1.f + __expf(-g))) * u;
          hbuf[base + (ni << 4)] = f2bf(hv);
        }
      }
    }
  }
}

// ---------------- gemm2: out[token] = (h @ Wd) * top_w ----------------
__global__ __launch_bounds__(512, 4) void gemm2_kernel(
    const unsigned short* __restrict__ hbuf, const float* __restrict__ Wd,
    const int* __restrict__ tiles, const int* __restrict__ sorted,
    const float* __restrict__ topw, float* __restrict__ out) {
  const int slot = blockIdx.x;
  const int e = tiles[slot * 3 + 0];
  const int row0 = tiles[slot * 3 + 1];
  const int nvalid = tiles[slot * 3 + 2];
  if (nvalid == 0) return;
  const int n0 = blockIdx.y * BN;

  __shared__ __align__(16) unsigned short As[BM][LDK];
  __shared__ __align__(16) unsigned short Bs[BN][LDK];

  const int t = threadIdx.x;
  const int arow = t >> 1;
  const int ah = (t & 1) << 4;
  const int bn = t & 63;
  const int bkq = (t >> 6) << 2;
  const float* __restrict__ Wde = Wd + (size_t)e * DF * DM;

  const int wv = t >> 6, lane = t & 63;
  const int wrow = (wv >> 1) << 6, wcol = (wv & 1) << 5;
  const int lr = lane & 15, lk = (lane >> 4) << 3;

  f32x4 acc[4][2];
#pragma unroll
  for (int mi = 0; mi < 4; mi++)
#pragma unroll
    for (int ni = 0; ni < 2; ni++) acc[mi][ni] = (f32x4){0.f, 0.f, 0.f, 0.f};

  const unsigned short* __restrict__ hrow =
      hbuf + (size_t)(row0 + (arow < nvalid ? arow : 0)) * DF;

  for (int k0 = 0; k0 < DF; k0 += BK) {
    // stage A from h (already bf16): two 16B copies per thread
    {
      short8 v0 = (short8){0,0,0,0,0,0,0,0}, v1 = v0;
      if (arow < nvalid) {
        v0 = *(const short8*)(hrow + k0 + ah);
        v1 = *(const short8*)(hrow + k0 + ah + 8);
      }
      *(short8*)&As[arow][ah] = v0;
      *(short8*)&As[arow][ah + 8] = v1;
    }
    // stage B from Wd
    {
      const float* pd = Wde + (size_t)(k0 + bkq) * DM + n0 + bn;
      ushort4 vd;
      vd.x = f2bf(pd[0]);
      vd.y = f2bf(pd[(size_t)DM]);
      vd.z = f2bf(pd[(size_t)2 * DM]);
      vd.w = f2bf(pd[(size_t)3 * DM]);
      *(ushort4*)&Bs[bn][bkq] = vd;
    }
    __syncthreads();

    short8 af[4], bf2[2];
#pragma unroll
    for (int mi = 0; mi < 4; mi++)
      af[mi] = *(const short8*)&As[wrow + (mi << 4) + lr][lk];
#pragma unroll
    for (int ni = 0; ni < 2; ni++)
      bf2[ni] = *(const short8*)&Bs[wcol + (ni << 4) + lr][lk];
#pragma unroll
    for (int mi = 0; mi < 4; mi++)
#pragma unroll
      for (int ni = 0; ni < 2; ni++)
        acc[mi][ni] = __builtin_amdgcn_mfma_f32_16x16x32_bf16(af[mi], bf2[ni], acc[mi][ni], 0, 0, 0);
    __syncthreads();
  }

  const int l4 = (lane >> 4) << 2;
#pragma unroll
  for (int mi = 0; mi < 4; mi++) {
#pragma unroll
    for (int r = 0; r < 4; r++) {
      int lrow = wrow + (mi << 4) + l4 + r;
      if (lrow < nvalid) {
        int tok = sorted[row0 + lrow];
        float w = topw[tok];
        size_t base = (size_t)tok * DM + n0 + wcol + lr;
#pragma unroll
        for (int ni = 0; ni < 2; ni++)
          out[base + (ni << 4)] = acc[mi][ni][r] * w;
      }
    }
  }
}

extern "C" void kernel_launch(void* const* d_in, const int* in_sizes, int n_in,
                              void* d_out, int out_size, void* d_ws, size_t ws_size,
                              hipStream_t stream) {
  const float* x  = (const float*)d_in[0];
  const float* Wr = (const float*)d_in[1];
  const float* br = (const float*)d_in[2];
  const float* Wg = (const float*)d_in[3];
  const float* Wu = (const float*)d_in[4];
  const float* Wd = (const float*)d_in[5];
  float* out = (float*)d_out;

  // workspace layout
  const size_t H_BYTES = (size_t)T_TOK * DF * 2;        // 64 MiB bf16 h
  unsigned short* hbuf = (unsigned short*)d_ws;
  int* meta = (int*)((char*)d_ws + H_BYTES);
  int* top_idx = meta;                 // 4096
  int* sorted  = meta + 4096;          // 4096
  int* counts  = meta + 8192;          // 4
  int* offs    = meta + 8196;          // 5
  int* cursors = meta + 8201;          // 4
  int* tiles   = meta + 8208;          // MAX_TILES*3
  float* topw  = (float*)(meta + 8320);// 4096

  hipMemsetAsync(counts, 0, NE * sizeof(int), stream);
  router_kernel<<<dim3((T_TOK * 64) / 256), 256, 0, stream>>>(x, Wr, br, top_idx, topw, counts);
  scan_kernel<<<1, 1, 0, stream>>>(counts, offs, cursors, tiles);
  scatter_kernel<<<dim3(T_TOK / 256), 256, 0, stream>>>(top_idx, cursors, sorted);
  gemm1_kernel<<<dim3(MAX_TILES, DF / BN), 512, 0, stream>>>(x, Wg, Wu, tiles, sorted, hbuf);
  gemm2_kernel<<<dim3(MAX_TILES, DM / BN), 512, 0, stream>>>(hbuf, Wd, tiles, sorted, topw, out);
}

// Round 3
// 1009.042 us; speedup vs baseline: 1.5709x; 1.2762x over previous
//
#include <hip/hip_runtime.h>

#define T_TOK 4096
#define DM 2048
#define DF 8192
#define NE 4
#define BM 256
#define BN 64
#define BKO 32        // old-path BK
#define BKN 64        // new-path BK
#define MAX_TILES 20
#define PADROWS 256
#define LDK (BKO + 8)

typedef __attribute__((ext_vector_type(8))) short short8;
typedef __attribute__((ext_vector_type(4))) float f32x4;

__device__ __forceinline__ unsigned short f2bf(float f) {
  unsigned int u = __float_as_uint(f);
  u += 0x7fffu + ((u >> 16) & 1u);   // round-to-nearest-even
  return (unsigned short)(u >> 16);
}

// async global->LDS, 16B per lane; LDS base must be wave-uniform (HW writes base + lane*16)
__device__ __forceinline__ void gld_lds16(const unsigned short* g, unsigned short* l) {
  __builtin_amdgcn_global_load_lds(
      (const __attribute__((address_space(1))) unsigned int*)g,
      (__attribute__((address_space(3))) unsigned int*)l, 16, 0, 0);
}

// ---------------- router: one wave per token, fp32 ----------------
__global__ __launch_bounds__(256) void router_kernel(
    const float* __restrict__ x, const float* __restrict__ Wr,
    const float* __restrict__ br, int* __restrict__ top_idx,
    float* __restrict__ top_w, int* __restrict__ counts) {
  int tok = (blockIdx.x * blockDim.x + threadIdx.x) >> 6;
  int lane = threadIdx.x & 63;
  if (tok >= T_TOK) return;
  const float* xr = x + (size_t)tok * DM;
  float s0 = 0.f, s1 = 0.f, s2 = 0.f, s3 = 0.f;
  for (int j = lane; j < DM; j += 64) {
    float xv = xr[j];
    float4 w = *(const float4*)(Wr + (size_t)j * NE);
    s0 += xv * w.x; s1 += xv * w.y; s2 += xv * w.z; s3 += xv * w.w;
  }
#pragma unroll
  for (int off = 32; off > 0; off >>= 1) {
    s0 += __shfl_xor(s0, off);
    s1 += __shfl_xor(s1, off);
    s2 += __shfl_xor(s2, off);
    s3 += __shfl_xor(s3, off);
  }
  if (lane == 0) {
    float l[NE] = {s0 + br[0], s1 + br[1], s2 + br[2], s3 + br[3]};
    int bi = 0; float bm = l[0];
#pragma unroll
    for (int e = 1; e < NE; e++) if (l[e] > bm) { bm = l[e]; bi = e; }
    float s = 0.f;
#pragma unroll
    for (int e = 0; e < NE; e++) s += __expf(l[e] - bm);
    top_idx[tok] = bi;
    top_w[tok] = 1.0f / s;
    atomicAdd(&counts[bi], 1);
  }
}

// ---------------- scan ----------------
__global__ void scan_kernel(const int* __restrict__ counts, int* __restrict__ offs,
                            int* __restrict__ cursors, int* __restrict__ tiles) {
  if (threadIdx.x != 0 || blockIdx.x != 0) return;
  int offv[NE + 1];
  offv[0] = 0;
  for (int e = 0; e < NE; e++) offv[e + 1] = offv[e] + counts[e];
  for (int e = 0; e <= NE; e++) offs[e] = offv[e];
  for (int e = 0; e < NE; e++) cursors[e] = offv[e];
  int nt = 0;
  for (int e = 0; e < NE; e++) {
    int c = counts[e];
    for (int s = 0; s < c; s += BM) {
      tiles[nt * 3 + 0] = e;
      tiles[nt * 3 + 1] = offv[e] + s;
      tiles[nt * 3 + 2] = (c - s < BM) ? (c - s) : BM;
      nt++;
    }
  }
  for (; nt < MAX_TILES; nt++) {
    tiles[nt * 3 + 0] = 0; tiles[nt * 3 + 1] = 0; tiles[nt * 3 + 2] = 0;
  }
}

// ---------------- scatter ----------------
__global__ __launch_bounds__(256) void scatter_kernel(
    const int* __restrict__ top_idx, int* __restrict__ cursors,
    int* __restrict__ sorted) {
  int t = blockIdx.x * blockDim.x + threadIdx.x;
  if (t >= T_TOK) return;
  int e = top_idx[t];
  int p = atomicAdd(&cursors[e], 1);
  sorted[p] = t;
}

// ---------------- gather_x: xs[p][k] = bf16(x[sorted[p]][k]), pad rows zeroed ----------------
__global__ __launch_bounds__(256) void gather_x_kernel(
    const float* __restrict__ x, const int* __restrict__ sorted,
    unsigned short* __restrict__ xs) {
  const int row = blockIdx.x;
  const int t = threadIdx.x;
  unsigned short* orow = xs + (size_t)row * DM + (t << 3);
  if (row >= T_TOK) {
    ushort4 z; z.x = 0; z.y = 0; z.z = 0; z.w = 0;
    *(ushort4*)orow = z;
    *(ushort4*)(orow + 4) = z;
    return;
  }
  const float* irow = x + (size_t)sorted[row] * DM + (t << 3);
  float4 a = *(const float4*)irow;
  float4 b = *(const float4*)(irow + 4);
  ushort4 p0, p1;
  p0.x = f2bf(a.x); p0.y = f2bf(a.y); p0.z = f2bf(a.z); p0.w = f2bf(a.w);
  p1.x = f2bf(b.x); p1.y = f2bf(b.y); p1.z = f2bf(b.z); p1.w = f2bf(b.w);
  *(ushort4*)orow = p0;
  *(ushort4*)(orow + 4) = p1;
}

// ---------------- transpose+convert: in fp32 [R][C] -> out bf16 [C][R], per z-matrix ----------------
__global__ __launch_bounds__(256) void transpose_cvt_kernel(
    const float* __restrict__ in, unsigned short* __restrict__ out, int R, int C) {
  __shared__ float tile[64][68];
  const size_t eo = (size_t)blockIdx.z * (size_t)R * (size_t)C;
  const float* inp = in + eo;
  unsigned short* outp = out + eo;
  const int r0 = blockIdx.y << 6, c0 = blockIdx.x << 6;
  const int t = threadIdx.x;
  const int lrow = t >> 4, lcol = (t & 15) << 2;
#pragma unroll
  for (int i = 0; i < 4; i++) {
    float4 v = *(const float4*)(inp + (size_t)(r0 + (i << 4) + lrow) * C + c0 + lcol);
    *(float4*)&tile[(i << 4) + lrow][lcol] = v;
  }
  __syncthreads();
  const int gg = t & 7, cc = t >> 3;
#pragma unroll
  for (int cp = 0; cp < 2; cp++) {
    int c = cc + (cp << 5);
    ushort4 pa, pb;
    pa.x = f2bf(tile[(gg << 3) + 0][c]);
    pa.y = f2bf(tile[(gg << 3) + 1][c]);
    pa.z = f2bf(tile[(gg << 3) + 2][c]);
    pa.w = f2bf(tile[(gg << 3) + 3][c]);
    pb.x = f2bf(tile[(gg << 3) + 4][c]);
    pb.y = f2bf(tile[(gg << 3) + 5][c]);
    pb.z = f2bf(tile[(gg << 3) + 6][c]);
    pb.w = f2bf(tile[(gg << 3) + 7][c]);
    unsigned short* po = outp + (size_t)(c0 + c) * R + r0 + (gg << 3);
    *(ushort4*)po = pa;
    *(ushort4*)(po + 4) = pb;
  }
}

// ---------------- gemm1 (bf16 path): h = silu(xs@Wg')*(xs@Wu') ----------------
// xs: [4096+pad][DM] bf16 sorted; wg/wu: [E][DF][DM] bf16 (column-major per expert)
__global__ __launch_bounds__(512, 4) void gemm1_bf16_kernel(
    const unsigned short* __restrict__ xs, const unsigned short* __restrict__ wg,
    const unsigned short* __restrict__ wu, const int* __restrict__ tiles,
    unsigned short* __restrict__ hbuf) {
  const int slot = blockIdx.x;
  const int e = tiles[slot * 3 + 0];
  const int row0 = tiles[slot * 3 + 1];
  const int nvalid = tiles[slot * 3 + 2];
  if (nvalid == 0) return;
  const int n0 = blockIdx.y * BN;

  __shared__ __align__(16) unsigned short As[BM * BKN];
  __shared__ __align__(16) unsigned short Bg[BN * BKN];
  __shared__ __align__(16) unsigned short Bu[BN * BKN];

  const int t = threadIdx.x;
  const int w = t >> 6, lane = t & 63;
  const int l3 = lane >> 3, l7 = lane & 7;
  const int swz = l7 ^ l3;                 // source granule for LDS granule l7 at row (..+l3)
  const int lr = lane & 15;
  const int wrow = (w >> 1) << 6, wcol = (w & 1) << 5;

  const unsigned short* wge = wg + (size_t)e * DM * DF;
  const unsigned short* wue = wu + (size_t)e * DM * DF;

  // per-lane global source bases (element units); +k0 walks K
  const unsigned short* aSrc = xs + (size_t)(row0 + (w << 5) + l3) * DM + (swz << 3);
  const unsigned short* bgSrc = wge + (size_t)(n0 + (w << 3) + l3) * DM + (swz << 3);
  const unsigned short* buSrc = wue + (size_t)(n0 + (w << 3) + l3) * DM + (swz << 3);

  f32x4 accg[4][2], accu[4][2];
#pragma unroll
  for (int mi = 0; mi < 4; mi++)
#pragma unroll
    for (int ni = 0; ni < 2; ni++) {
      accg[mi][ni] = (f32x4){0.f, 0.f, 0.f, 0.f};
      accu[mi][ni] = (f32x4){0.f, 0.f, 0.f, 0.f};
    }

  for (int k0 = 0; k0 < DM; k0 += BKN) {
    // stage: A = 4 chunks/wave, Bg/Bu = 1 chunk/wave (1 KB each, linear)
#pragma unroll
    for (int j = 0; j < 4; j++)
      gld_lds16(aSrc + (size_t)(j << 3) * DM + k0, &As[(((w << 2) + j) << 9)]);
    gld_lds16(bgSrc + k0, &Bg[w << 9]);
    gld_lds16(buSrc + k0, &Bu[w << 9]);
    __syncthreads();

#pragma unroll
    for (int h = 0; h < 2; h++) {
      const int gbase = (h << 2) + (lane >> 4);
      const int g = gbase ^ (lr & 7);      // swizzled read granule
      short8 af[4], bgf[2], buf2[2];
#pragma unroll
      for (int mi = 0; mi < 4; mi++) {
        int row = wrow + (mi << 4) + lr;
        af[mi] = *(const short8*)&As[(row << 6) + (g << 3)];
      }
#pragma unroll
      for (int ni = 0; ni < 2; ni++) {
        int row = wcol + (ni << 4) + lr;
        bgf[ni]  = *(const short8*)&Bg[(row << 6) + (g << 3)];
        buf2[ni] = *(const short8*)&Bu[(row << 6) + (g << 3)];
      }
#pragma unroll
      for (int mi = 0; mi < 4; mi++)
#pragma unroll
        for (int ni = 0; ni < 2; ni++) {
          accg[mi][ni] = __builtin_amdgcn_mfma_f32_16x16x32_bf16(af[mi], bgf[ni], accg[mi][ni], 0, 0, 0);
          accu[mi][ni] = __builtin_amdgcn_mfma_f32_16x16x32_bf16(af[mi], buf2[ni], accu[mi][ni], 0, 0, 0);
        }
    }
    __syncthreads();
  }

  const int l4 = (lane >> 4) << 2;
#pragma unroll
  for (int mi = 0; mi < 4; mi++) {
#pragma unroll
    for (int r = 0; r < 4; r++) {
      int lrow = wrow + (mi << 4) + l4 + r;
      if (lrow < nvalid) {
        size_t base = (size_t)(row0 + lrow) * DF + n0 + wcol + lr;
#pragma unroll
        for (int ni = 0; ni < 2; ni++) {
          float gv = accg[mi][ni][r];
          float uv = accu[mi][ni][r];
          float hv = (gv / (1.f + __expf(-gv))) * uv;
          hbuf[base + (ni << 4)] = f2bf(hv);
        }
      }
    }
  }
}

// ---------------- gemm2 (bf16 path): out[token] = (h @ Wd') * top_w ----------------
// hbuf: [4096+pad][DF] bf16 sorted; wd: [E][DM][DF] bf16
__global__ __launch_bounds__(512, 4) void gemm2_bf16_kernel(
    const unsigned short* __restrict__ hbuf, const unsigned short* __restrict__ wd,
    const int* __restrict__ tiles, const int* __restrict__ sorted,
    const float* __restrict__ topw, float* __restrict__ out) {
  const int slot = blockIdx.x;
  const int e = tiles[slot * 3 + 0];
  const int row0 = tiles[slot * 3 + 1];
  const int nvalid = tiles[slot * 3 + 2];
  if (nvalid == 0) return;
  const int n0 = blockIdx.y * BN;

  __shared__ __align__(16) unsigned short As[BM * BKN];
  __shared__ __align__(16) unsigned short Bs[BN * BKN];

  const int t = threadIdx.x;
  const int w = t >> 6, lane = t & 63;
  const int l3 = lane >> 3, l7 = lane & 7;
  const int swz = l7 ^ l3;
  const int lr = lane & 15;
  const int wrow = (w >> 1) << 6, wcol = (w & 1) << 5;

  const unsigned short* wde = wd + (size_t)e * DM * DF;
  const unsigned short* aSrc = hbuf + (size_t)(row0 + (w << 5) + l3) * DF + (swz << 3);
  const unsigned short* bSrc = wde + (size_t)(n0 + (w << 3) + l3) * DF + (swz << 3);

  f32x4 acc[4][2];
#pragma unroll
  for (int mi = 0; mi < 4; mi++)
#pragma unroll
    for (int ni = 0; ni < 2; ni++) acc[mi][ni] = (f32x4){0.f, 0.f, 0.f, 0.f};

  for (int k0 = 0; k0 < DF; k0 += BKN) {
#pragma unroll
    for (int j = 0; j < 4; j++)
      gld_lds16(aSrc + (size_t)(j << 3) * DF + k0, &As[(((w << 2) + j) << 9)]);
    gld_lds16(bSrc + k0, &Bs[w << 9]);
    __syncthreads();

#pragma unroll
    for (int h = 0; h < 2; h++) {
      const int gbase = (h << 2) + (lane >> 4);
      const int g = gbase ^ (lr & 7);
      short8 af[4], bf2[2];
#pragma unroll
      for (int mi = 0; mi < 4; mi++) {
        int row = wrow + (mi << 4) + lr;
        af[mi] = *(const short8*)&As[(row << 6) + (g << 3)];
      }
#pragma unroll
      for (int ni = 0; ni < 2; ni++) {
        int row = wcol + (ni << 4) + lr;
        bf2[ni] = *(const short8*)&Bs[(row << 6) + (g << 3)];
      }
#pragma unroll
      for (int mi = 0; mi < 4; mi++)
#pragma unroll
        for (int ni = 0; ni < 2; ni++)
          acc[mi][ni] = __builtin_amdgcn_mfma_f32_16x16x32_bf16(af[mi], bf2[ni], acc[mi][ni], 0, 0, 0);
    }
    __syncthreads();
  }

  const int l4 = (lane >> 4) << 2;
#pragma unroll
  for (int mi = 0; mi < 4; mi++) {
#pragma unroll
    for (int r = 0; r < 4; r++) {
      int lrow = wrow + (mi << 4) + l4 + r;
      if (lrow < nvalid) {
        int tok = sorted[row0 + lrow];
        float wv = topw[tok];
        size_t base = (size_t)tok * DM + n0 + wcol + lr;
#pragma unroll
        for (int ni = 0; ni < 2; ni++)
          out[base + (ni << 4)] = acc[mi][ni][r] * wv;
      }
    }
  }
}

// ================= fallback (R1) fp32-weight kernels =================
__global__ __launch_bounds__(512, 4) void gemm1_f32_kernel(
    const float* __restrict__ x, const float* __restrict__ Wg,
    const float* __restrict__ Wu, const int* __restrict__ tiles,
    const int* __restrict__ sorted, unsigned short* __restrict__ hbuf) {
  const int slot = blockIdx.x;
  const int e = tiles[slot * 3 + 0];
  const int row0 = tiles[slot * 3 + 1];
  const int nvalid = tiles[slot * 3 + 2];
  if (nvalid == 0) return;
  const int n0 = blockIdx.y * BN;

  __shared__ __align__(16) unsigned short As[BM][LDK];
  __shared__ __align__(16) unsigned short Bg[BN][LDK];
  __shared__ __align__(16) unsigned short Bu[BN][LDK];

  const int t = threadIdx.x;
  const int arow = t >> 1;
  const int ah = (t & 1) << 4;
  const int atok = (arow < nvalid) ? sorted[row0 + arow] : -1;
  const float* __restrict__ xrow = x + (size_t)(atok >= 0 ? atok : 0) * DM;
  const int bn = t & 63;
  const int bkq = (t >> 6) << 2;

  const size_t eo = (size_t)e * DM * DF;
  const float* __restrict__ Wge = Wg + eo;
  const float* __restrict__ Wue = Wu + eo;

  const int wv = t >> 6, lane = t & 63;
  const int wrow = (wv >> 1) << 6, wcol = (wv & 1) << 5;
  const int lr = lane & 15, lk = (lane >> 4) << 3;

  f32x4 accg[4][2], accu[4][2];
#pragma unroll
  for (int mi = 0; mi < 4; mi++)
#pragma unroll
    for (int ni = 0; ni < 2; ni++) {
      accg[mi][ni] = (f32x4){0.f, 0.f, 0.f, 0.f};
      accu[mi][ni] = (f32x4){0.f, 0.f, 0.f, 0.f};
    }

  for (int k0 = 0; k0 < DM; k0 += BKO) {
#pragma unroll
    for (int j = 0; j < 4; j++) {
      float4 v = make_float4(0.f, 0.f, 0.f, 0.f);
      if (atok >= 0) v = *(const float4*)(xrow + k0 + ah + (j << 2));
      ushort4 pv;
      pv.x = f2bf(v.x); pv.y = f2bf(v.y); pv.z = f2bf(v.z); pv.w = f2bf(v.w);
      *(ushort4*)&As[arow][ah + (j << 2)] = pv;
    }
    {
      const float* pg = Wge + (size_t)(k0 + bkq) * DF + n0 + bn;
      const float* pu = Wue + (size_t)(k0 + bkq) * DF + n0 + bn;
      ushort4 vg, vu;
      vg.x = f2bf(pg[0]);              vu.x = f2bf(pu[0]);
      vg.y = f2bf(pg[(size_t)DF]);     vu.y = f2bf(pu[(size_t)DF]);
      vg.z = f2bf(pg[(size_t)2 * DF]); vu.z = f2bf(pu[(size_t)2 * DF]);
      vg.w = f2bf(pg[(size_t)3 * DF]); vu.w = f2bf(pu[(size_t)3 * DF]);
      *(ushort4*)&Bg[bn][bkq] = vg;
      *(ushort4*)&Bu[bn][bkq] = vu;
    }
    __syncthreads();

    short8 af[4], bgf[2], buf2[2];
#pragma unroll
    for (int mi = 0; mi < 4; mi++)
      af[mi] = *(const short8*)&As[wrow + (mi << 4) + lr][lk];
#pragma unroll
    for (int ni = 0; ni < 2; ni++) {
      bgf[ni]  = *(const short8*)&Bg[wcol + (ni << 4) + lr][lk];
      buf2[ni] = *(const short8*)&Bu[wcol + (ni << 4) + lr][lk];
    }
#pragma unroll
    for (int mi = 0; mi < 4; mi++)
#pragma unroll
      for (int ni = 0; ni < 2; ni++) {
        accg[mi][ni] = __builtin_amdgcn_mfma_f32_16x16x32_bf16(af[mi], bgf[ni], accg[mi][ni], 0, 0, 0);
        accu[mi][ni] = __builtin_amdgcn_mfma_f32_16x16x32_bf16(af[mi], buf2[ni], accu[mi][ni], 0, 0, 0);
      }
    __syncthreads();
  }

  const int l4 = (lane >> 4) << 2;
#pragma unroll
  for (int mi = 0; mi < 4; mi++) {
#pragma unroll
    for (int r = 0; r < 4; r++) {
      int lrow = wrow + (mi << 4) + l4 + r;
      if (lrow < nvalid) {
        size_t base = (size_t)(row0 + lrow) * DF + n0 + wcol + lr;
#pragma unroll
        for (int ni = 0; ni < 2; ni++) {
          float g = accg[mi][ni][r];
          float u = accu[mi][ni][r];
          float hv = (g / (1.f + __expf(-g))) * u;
          hbuf[base + (ni << 4)] = f2bf(hv);
        }
      }
    }
  }
}

__global__ __launch_bounds__(512, 4) void gemm2_f32_kernel(
    const unsigned short* __restrict__ hbuf, const float* __restrict__ Wd,
    const int* __restrict__ tiles, const int* __restrict__ sorted,
    const float* __restrict__ topw, float* __restrict__ out) {
  const int slot = blockIdx.x;
  const int e = tiles[slot * 3 + 0];
  const int row0 = tiles[slot * 3 + 1];
  const int nvalid = tiles[slot * 3 + 2];
  if (nvalid == 0) return;
  const int n0 = blockIdx.y * BN;

  __shared__ __align__(16) unsigned short As[BM][LDK];
  __shared__ __align__(16) unsigned short Bs[BN][LDK];

  const int t = threadIdx.x;
  const int arow = t >> 1;
  const int ah = (t & 1) << 4;
  const int bn = t & 63;
  const int bkq = (t >> 6) << 2;
  const float* __restrict__ Wde = Wd + (size_t)e * DF * DM;

  const int wv = t >> 6, lane = t & 63;
  const int wrow = (wv >> 1) << 6, wcol = (wv & 1) << 5;
  const int lr = lane & 15, lk = (lane >> 4) << 3;

  f32x4 acc[4][2];
#pragma unroll
  for (int mi = 0; mi < 4; mi++)
#pragma unroll
    for (int ni = 0; ni < 2; ni++) acc[mi][ni] = (f32x4){0.f, 0.f, 0.f, 0.f};

  const unsigned short* __restrict__ hrow =
      hbuf + (size_t)(row0 + (arow < nvalid ? arow : 0)) * DF;

  for (int k0 = 0; k0 < DF; k0 += BKO) {
    {
      short8 v0 = (short8){0,0,0,0,0,0,0,0}, v1 = v0;
      if (arow < nvalid) {
        v0 = *(const short8*)(hrow + k0 + ah);
        v1 = *(const short8*)(hrow + k0 + ah + 8);
      }
      *(short8*)&As[arow][ah] = v0;
      *(short8*)&As[arow][ah + 8] = v1;
    }
    {
      const float* pd = Wde + (size_t)(k0 + bkq) * DM + n0 + bn;
      ushort4 vd;
      vd.x = f2bf(pd[0]);
      vd.y = f2bf(pd[(size_t)DM]);
      vd.z = f2bf(pd[(size_t)2 * DM]);
      vd.w = f2bf(pd[(size_t)3 * DM]);
      *(ushort4*)&Bs[bn][bkq] = vd;
    }
    __syncthreads();

    short8 af[4], bf2[2];
#pragma unroll
    for (int mi = 0; mi < 4; mi++)
      af[mi] = *(const short8*)&As[wrow + (mi << 4) + lr][lk];
#pragma unroll
    for (int ni = 0; ni < 2; ni++)
      bf2[ni] = *(const short8*)&Bs[wcol + (ni << 4) + lr][lk];
#pragma unroll
    for (int mi = 0; mi < 4; mi++)
#pragma unroll
      for (int ni = 0; ni < 2; ni++)
        acc[mi][ni] = __builtin_amdgcn_mfma_f32_16x16x32_bf16(af[mi], bf2[ni], acc[mi][ni], 0, 0, 0);
    __syncthreads();
  }

  const int l4 = (lane >> 4) << 2;
#pragma unroll
  for (int mi = 0; mi < 4; mi++) {
#pragma unroll
    for (int r = 0; r < 4; r++) {
      int lrow = wrow + (mi << 4) + l4 + r;
      if (lrow < nvalid) {
        int tok = sorted[row0 + lrow];
        float w = topw[tok];
        size_t base = (size_t)tok * DM + n0 + wcol + lr;
#pragma unroll
        for (int ni = 0; ni < 2; ni++)
          out[base + (ni << 4)] = acc[mi][ni][r] * w;
      }
    }
  }
}

extern "C" void kernel_launch(void* const* d_in, const int* in_sizes, int n_in,
                              void* d_out, int out_size, void* d_ws, size_t ws_size,
                              hipStream_t stream) {
  const float* x  = (const float*)d_in[0];
  const float* Wr = (const float*)d_in[1];
  const float* br = (const float*)d_in[2];
  const float* Wg = (const float*)d_in[3];
  const float* Wu = (const float*)d_in[4];
  const float* Wd = (const float*)d_in[5];
  float* out = (float*)d_out;

  const size_t XS_ELEMS = (size_t)(T_TOK + PADROWS) * DM;
  const size_t HB_ELEMS = (size_t)(T_TOK + PADROWS) * DF;
  const size_t W_ELEMS  = (size_t)NE * DM * DF;
  const size_t NEED = (XS_ELEMS + HB_ELEMS + 3 * W_ELEMS) * 2 + (1 << 20);

  if (ws_size >= NEED) {
    // ---------- bf16 fast path ----------
    unsigned short* xs = (unsigned short*)d_ws;
    unsigned short* hb = xs + XS_ELEMS;
    unsigned short* wg = hb + HB_ELEMS;
    unsigned short* wu = wg + W_ELEMS;
    unsigned short* wd = wu + W_ELEMS;
    int* meta = (int*)(wd + W_ELEMS);
    int* top_idx = meta;
    int* sorted  = meta + 4096;
    int* counts  = meta + 8192;
    int* offs    = meta + 8196;
    int* cursors = meta + 8201;
    int* tiles   = meta + 8208;
    float* topw  = (float*)(meta + 8320);

    hipMemsetAsync(counts, 0, NE * sizeof(int), stream);
    router_kernel<<<dim3((T_TOK * 64) / 256), 256, 0, stream>>>(x, Wr, br, top_idx, topw, counts);
    scan_kernel<<<1, 1, 0, stream>>>(counts, offs, cursors, tiles);
    scatter_kernel<<<dim3(T_TOK / 256), 256, 0, stream>>>(top_idx, cursors, sorted);
    gather_x_kernel<<<dim3(T_TOK + PADROWS), 256, 0, stream>>>(x, sorted, xs);
    // Wg/Wu: [E][DM][DF] -> [E][DF][DM]
    transpose_cvt_kernel<<<dim3(DF / 64, DM / 64, NE), 256, 0, stream>>>(Wg, wg, DM, DF);
    transpose_cvt_kernel<<<dim3(DF / 64, DM / 64, NE), 256, 0, stream>>>(Wu, wu, DM, DF);
    // Wd: [E][DF][DM] -> [E][DM][DF]
    transpose_cvt_kernel<<<dim3(DM / 64, DF / 64, NE), 256, 0, stream>>>(Wd, wd, DF, DM);
    gemm1_bf16_kernel<<<dim3(MAX_TILES, DF / BN), 512, 0, stream>>>(xs, wg, wu, tiles, hb);
    gemm2_bf16_kernel<<<dim3(MAX_TILES, DM / BN), 512, 0, stream>>>(hb, wd, tiles, sorted, topw, out);
  } else {
    // ---------- fallback (R1) path ----------
    const size_t H_BYTES = (size_t)T_TOK * DF * 2;
    unsigned short* hbuf = (unsigned short*)d_ws;
    int* meta = (int*)((char*)d_ws + H_BYTES);
    int* top_idx = meta;
    int* sorted  = meta + 4096;
    int* counts  = meta + 8192;
    int* offs    = meta + 8196;
    int* cursors = meta + 8201;
    int* tiles   = meta + 8208;
    float* topw  = (float*)(meta + 8320);

    hipMemsetAsync(counts, 0, NE * sizeof(int), stream);
    router_kernel<<<dim3((T_TOK * 64) / 256), 256, 0, stream>>>(x, Wr, br, top_idx, topw, counts);
    scan_kernel<<<1, 1, 0, stream>>>(counts, offs, cursors, tiles);
    scatter_kernel<<<dim3(T_TOK / 256), 256, 0, stream>>>(top_idx, cursors, sorted);
    gemm1_f32_kernel<<<dim3(MAX_TILES, DF / BN), 512, 0, stream>>>(x, Wg, Wu, tiles, sorted, hbuf);
    gemm2_f32_kernel<<<dim3(MAX_TILES, DM / BN), 512, 0, stream>>>(hbuf, Wd, tiles, sorted, topw, out);
  }
}